// Round 1
// 198.131 us; speedup vs baseline: 1.0424x; 1.0424x over previous
//
#include <hip/hip_runtime.h>

#define D  128
#define NF 3
#define V  8

typedef __attribute__((ext_vector_type(8))) short short8;
typedef __attribute__((ext_vector_type(4))) float f32x4;

__device__ inline unsigned short f2bf(float x) {
    unsigned u = __builtin_bit_cast(unsigned, x);
    return (unsigned short)((u + 0x7FFFu + ((u >> 16) & 1u)) >> 16);   // RNE
}
__device__ inline float bflo(unsigned u) {
    return __builtin_bit_cast(float, u << 16);
}
__device__ inline float bfhi(unsigned u) {
    return __builtin_bit_cast(float, u & 0xFFFF0000u);
}

// ---------------- build: hist+pack + tables + bf16 convert ----------------
// roles by blockIdx: [0,eb) hist atomics + edge-record pack (merged);
// [eb,eb+256) combined emb table Tb; [.., +64) W->B-frag WB;
// rest: nfeat fp32 -> bf16.

__global__ __launch_bounds__(256) void build_kernel(
    const int* __restrict__ src, const int* __restrict__ dst,
    const int* __restrict__ eidx, const float* __restrict__ emb,
    const float* __restrict__ Wm, const float* __restrict__ nfeat,
    int* __restrict__ count, unsigned* __restrict__ pkd,
    unsigned short* __restrict__ Tb, unsigned short* __restrict__ WB,
    unsigned* __restrict__ nfb32, int E, int eb)
{
    int b = blockIdx.x, t = threadIdx.x;
    if (b < eb) {
        int e = b * 256 + t;
        if (e < E) {
            atomicAdd(&count[dst[e]], 1);
            int i0 = eidx[e * NF + 0];
            int i1 = eidx[e * NF + 1];
            int i2 = eidx[e * NF + 2];
            pkd[e] = (unsigned)src[e]
                   | ((unsigned)(i0 + (i1 << 3) + (i2 << 6)) << 16);
        }
    } else if (b < eb + 256) {
        int tid = (b - eb) * 256 + t;              // 0..65535
        int cmb = tid >> 7, c = tid & 127;
        float s = emb[(cmb & 7) * D + c]
                + emb[(V + ((cmb >> 3) & 7)) * D + c]
                + emb[(2 * V + (cmb >> 6)) * D + c];
        Tb[tid] = f2bf(s);
    } else if (b < eb + 320) {
        // WB[((n*4+ks)*64+lane)*8+j] = bf16(W[ks*32+(lane>>4)*8+j][n*16+(lane&15)])
        int tid = (b - (eb + 256)) * 256 + t;      // 0..16383
        int j = tid & 7, lane = (tid >> 3) & 63, ks = (tid >> 9) & 3, n = tid >> 11;
        int k = ks * 32 + ((lane >> 4) << 3) + j;
        int c = n * 16 + (lane & 15);
        WB[tid] = f2bf(Wm[k * D + c]);
    } else {
        int tid = (b - (eb + 320)) * 256 + t;      // 4 floats each
        float4 v = ((const float4*)nfeat)[tid];
        nfb32[tid * 2 + 0] = (unsigned)f2bf(v.x) | ((unsigned)f2bf(v.y) << 16);
        nfb32[tid * 2 + 1] = (unsigned)f2bf(v.z) | ((unsigned)f2bf(v.w) << 16);
    }
}

// ---------------- single-pass scan (decoupled lookback) ----------------
// desc[b]: (sum<<2) | state; state 0=invalid, 1=aggregate, 2=inclusive prefix.

__global__ __launch_bounds__(256) void scan_kernel(
    const int* __restrict__ count, int* __restrict__ offset,
    int* __restrict__ cursor, unsigned* __restrict__ desc, int N)
{
    int b = blockIdx.x, t = threadIdx.x;
    int i = b * 256 + t;
    int c = (i < N) ? count[i] : 0;
    int lane = t & 63, wv = t >> 6;
    int inc = c;
#pragma unroll
    for (int d = 1; d < 64; d <<= 1) {
        int u = __shfl_up(inc, d);
        if (lane >= d) inc += u;
    }
    __shared__ int ws4[4];
    __shared__ int sprefix;
    if (lane == 63) ws4[wv] = inc;
    __syncthreads();
    int total = ws4[0] + ws4[1] + ws4[2] + ws4[3];
    int base = 0;
    for (int w = 0; w < wv; ++w) base += ws4[w];

    if (t == 0) {
        if (b == 0) {
            atomicExch(&desc[0], ((unsigned)total << 2) | 2u);
            sprefix = 0;
        } else {
            atomicExch(&desc[b], ((unsigned)total << 2) | 1u);   // aggregate first
        }
    }
    if (b > 0 && wv == 0) {
        int ex = 0;
        int j = b - 1;
        for (;;) {
            int idx = j - lane;
            unsigned v = 0;
            if (idx >= 0) {
                do { v = atomicAdd(&desc[idx], 0u); } while ((v & 3u) == 0u);
            }
            unsigned long long pm = __ballot(idx >= 0 && (v & 3u) == 2u);
            int contrib;
            if (pm) {
                int fl = (int)(__ffsll((unsigned long long)pm) - 1);
                contrib = (lane <= fl) ? (int)(v >> 2) : 0;
            } else {
                contrib = (idx >= 0) ? (int)(v >> 2) : 0;
            }
#pragma unroll
            for (int d = 32; d > 0; d >>= 1) contrib += __shfl_down(contrib, d);
            if (lane == 0) ex += contrib;
            if (pm) break;
            j -= 64;
        }
        if (lane == 0) {
            atomicExch(&desc[b], ((unsigned)(ex + total) << 2) | 2u);
            sprefix = ex;
        }
    }
    __syncthreads();
    if (i < N) {
        int exv = sprefix + base + inc - c;
        offset[i] = exv;
        cursor[i] = exv;
    }
}

// ---------------- scatter packed records into dst-sorted order --------------

__global__ __launch_bounds__(256) void scatter_kernel(
    const int* __restrict__ dst, const unsigned* __restrict__ pkd,
    int* __restrict__ cursor, unsigned* __restrict__ packed, int E)
{
    int e = blockIdx.x * 256 + threadIdx.x;
    if (e < E) {
        int pos = atomicAdd(&cursor[dst[e]], 1);
        packed[pos] = pkd[e];
    }
}

// ---------------- fused gather + MFMA projection ----------------
// Block = 16 nodes, 4 waves. Wave w gathers nodes row0+w*4..+3 into LDS h-tile,
// then computes cols [w*32, w*32+32) of the 16x128 output via MFMA.
// Phase 1 is latency-bound: unroll 8 edges (16 gathers in flight) and
// prefetch the next node's packed-record chunk to hide the 2-deep chain.

__global__ __launch_bounds__(256) void fused_gp(
    const float* __restrict__ nfeat,
    const unsigned* __restrict__ nfb32,
    const unsigned* __restrict__ Tb32,
    const unsigned* __restrict__ packed,
    const int* __restrict__ offset,
    const int* __restrict__ count,
    const unsigned short* __restrict__ WB,
    const float* __restrict__ bias,
    float* __restrict__ out, int N)
{
    __shared__ unsigned short hA[16][136];   // +8 pad
    int t = threadIdx.x, w = t >> 6, lane = t & 63;
    int quad = lane >> 4, l15 = lane & 15;
    int row0 = blockIdx.x * 16;

    // Hoist all per-node metadata loads (wave-uniform addresses).
    int offv[4], cntv[4];
#pragma unroll
    for (int i = 0; i < 4; ++i) {
        int n = row0 + w * 4 + i;
        offv[i] = (n < N) ? offset[n] : 0;
        cntv[i] = (n < N) ? count[n] : 0;
    }
    // Prefetch node 0's first record chunk.
    int m0 = (cntv[0] < 64) ? cntv[0] : 64;
    unsigned rec_next = (lane < m0) ? packed[offv[0] + lane] : 0u;

    // Phase 1: gather
    for (int i = 0; i < 4; ++i) {
        int n = row0 + w * 4 + i;
        if (n >= N) break;
        int off = offv[i], cnt = cntv[i];
        float2 acc = ((const float2*)nfeat)[n * 64 + lane];   // self term fp32
        unsigned rec = rec_next;
        if (i < 3) {   // prefetch next node's first chunk (hides rec latency)
            int m2 = (cntv[i + 1] < 64) ? cntv[i + 1] : 64;
            rec_next = (lane < m2) ? packed[offv[i + 1] + lane] : 0u;
        }
        int base = 0;
        for (;;) {
            int rem = cnt - base;
            int m = (rem < 64) ? rem : 64;
            int j = 0;
            for (; j + 8 <= m; j += 8) {   // 16 loads in flight
                unsigned u[8], av[8], tv[8];
#pragma unroll
                for (int q = 0; q < 8; ++q) u[q] = __shfl((int)rec, j + q);
#pragma unroll
                for (int q = 0; q < 8; ++q) {
                    av[q] = nfb32[(u[q] & 0xFFFFu) * 64 + lane];
                    tv[q] = Tb32[(u[q] >> 16) * 64 + lane];
                }
                float p0 = bflo(av[0]) + bflo(tv[0]);
                float p1 = bflo(av[1]) + bflo(tv[1]);
                float p2 = bflo(av[2]) + bflo(tv[2]);
                float p3 = bflo(av[3]) + bflo(tv[3]);
                float p4 = bflo(av[4]) + bflo(tv[4]);
                float p5 = bflo(av[5]) + bflo(tv[5]);
                float p6 = bflo(av[6]) + bflo(tv[6]);
                float p7 = bflo(av[7]) + bflo(tv[7]);
                acc.x += ((p0 + p1) + (p2 + p3)) + ((p4 + p5) + (p6 + p7));
                float q0 = bfhi(av[0]) + bfhi(tv[0]);
                float q1 = bfhi(av[1]) + bfhi(tv[1]);
                float q2 = bfhi(av[2]) + bfhi(tv[2]);
                float q3 = bfhi(av[3]) + bfhi(tv[3]);
                float q4 = bfhi(av[4]) + bfhi(tv[4]);
                float q5 = bfhi(av[5]) + bfhi(tv[5]);
                float q6 = bfhi(av[6]) + bfhi(tv[6]);
                float q7 = bfhi(av[7]) + bfhi(tv[7]);
                acc.y += ((q0 + q1) + (q2 + q3)) + ((q4 + q5) + (q6 + q7));
            }
            for (; j + 4 <= m; j += 4) {
                unsigned u0 = __shfl((int)rec, j);
                unsigned u1 = __shfl((int)rec, j + 1);
                unsigned u2 = __shfl((int)rec, j + 2);
                unsigned u3 = __shfl((int)rec, j + 3);
                unsigned a0 = nfb32[(u0 & 0xFFFFu) * 64 + lane];
                unsigned t0 = Tb32[(u0 >> 16) * 64 + lane];
                unsigned a1 = nfb32[(u1 & 0xFFFFu) * 64 + lane];
                unsigned t1 = Tb32[(u1 >> 16) * 64 + lane];
                unsigned a2 = nfb32[(u2 & 0xFFFFu) * 64 + lane];
                unsigned t2 = Tb32[(u2 >> 16) * 64 + lane];
                unsigned a3 = nfb32[(u3 & 0xFFFFu) * 64 + lane];
                unsigned t3 = Tb32[(u3 >> 16) * 64 + lane];
                acc.x += (bflo(a0) + bflo(t0)) + (bflo(a1) + bflo(t1))
                       + (bflo(a2) + bflo(t2)) + (bflo(a3) + bflo(t3));
                acc.y += (bfhi(a0) + bfhi(t0)) + (bfhi(a1) + bfhi(t1))
                       + (bfhi(a2) + bfhi(t2)) + (bfhi(a3) + bfhi(t3));
            }
            for (; j < m; ++j) {
                unsigned u = __shfl((int)rec, j);
                unsigned a = nfb32[(u & 0xFFFFu) * 64 + lane];
                unsigned tt = Tb32[(u >> 16) * 64 + lane];
                acc.x += bflo(a) + bflo(tt);
                acc.y += bfhi(a) + bfhi(tt);
            }
            base += 64;
            if (base >= cnt) break;
            int mn = cnt - base;
            mn = (mn < 64) ? mn : 64;
            rec = (lane < mn) ? packed[off + base + lane] : 0u;
        }
        float inv = 1.0f / (float)(cnt + 1);
        acc.x *= inv; acc.y *= inv;
        *(unsigned*)&hA[w * 4 + i][2 * lane] =
            (unsigned)f2bf(acc.x) | ((unsigned)f2bf(acc.y) << 16);
    }
    __syncthreads();

    // Phase 2: 16x128 = A(16x128) @ W(128x128) slice per wave.
    // B fragments loaded here (L2-hot 16 KB table) to keep phase-1 VGPRs <= 64.
    short8 a[4];
#pragma unroll
    for (int ks = 0; ks < 4; ++ks)
        a[ks] = *(const short8*)&hA[l15][ks * 32 + quad * 8];

#pragma unroll
    for (int ni = 0; ni < 2; ++ni) {
        int n = w * 2 + ni;
        f32x4 acc = {0.0f, 0.0f, 0.0f, 0.0f};
#pragma unroll
        for (int ks = 0; ks < 4; ++ks) {
            short8 bfr = *(const short8*)&WB[((n * 4 + ks) * 64 + lane) * 8];
            acc = __builtin_amdgcn_mfma_f32_16x16x32_bf16(a[ks], bfr, acc, 0, 0, 0);
        }
        float bv = bias[n * 16 + l15];
        int col = n * 16 + l15;
#pragma unroll
        for (int rg = 0; rg < 4; ++rg) {
            int row = row0 + quad * 4 + rg;
            if (row < N) out[row * D + col] = acc[rg] + bv;
        }
    }
}

extern "C" void kernel_launch(void* const* d_in, const int* in_sizes, int n_in,
                              void* d_out, int out_size, void* d_ws, size_t ws_size,
                              hipStream_t stream)
{
    const float* nfeat = (const float*)d_in[0];
    const int*   src   = (const int*)  d_in[1];
    const int*   dst   = (const int*)  d_in[2];
    const int*   eidx  = (const int*)  d_in[3];
    const float* emb   = (const float*)d_in[4];
    const float* Wm    = (const float*)d_in[5];
    const float* bias  = (const float*)d_in[6];
    float* out = (float*)d_out;

    int N = in_sizes[0] / D;   // 50000
    int E = in_sizes[1];       // 600000
    int eb = (E + 255) / 256;  // 2344
    int NB = (N + 255) / 256;  // 196

    // ws: count[N] | desc[256] | cursor[N] | offset[N] | pkd[E] | packed[E]
    //     | Tb[65536 u16] | WB[16384 u16] | nfb[N*128 u16]    (~18.4 MB)
    int* count = (int*)d_ws;
    unsigned* desc = (unsigned*)(count + N);
    int* cursor = (int*)(desc + 256);
    int* offset = cursor + N;
    unsigned* pkd = (unsigned*)(offset + N);
    unsigned* packed = pkd + E;
    unsigned short* Tb = (unsigned short*)(packed + E);
    unsigned short* WB = Tb + 512 * 128;
    unsigned* nfb32 = (unsigned*)(WB + 16384);

    // zero count[] and lookback descriptors in one contiguous memset
    hipMemsetAsync(count, 0, ((size_t)N + 256) * sizeof(int), stream);

    int nfb_blocks = (N * D / 4 + 255) / 256;   // 6250
    build_kernel<<<eb + 320 + nfb_blocks, 256, 0, stream>>>(
        src, dst, eidx, emb, Wm, nfeat, count, pkd, Tb, WB, nfb32, E, eb);
    scan_kernel<<<NB, 256, 0, stream>>>(count, offset, cursor, desc, N);
    scatter_kernel<<<eb, 256, 0, stream>>>(dst, pkd, cursor, packed, E);
    fused_gp<<<(N + 15) / 16, 256, 0, stream>>>(
        nfeat, nfb32, (const unsigned*)Tb, packed, offset, count,
        WB, bias, out, N);
}